// Round 1
// baseline (776.067 us; speedup 1.0000x reference)
//
#include <hip/hip_runtime.h>

// MeanAggregator on MI355X.
// Stages: degree scatter -> MLP (f32 LDS GEMM) -> edge scatter (atomics) -> divide.

constexpr int D = 128;

__global__ __launch_bounds__(256) void k_degree(const int* __restrict__ src,
                                                const int* __restrict__ dst,
                                                const int* __restrict__ indp,
                                                float* __restrict__ degree, int E) {
    int e = blockIdx.x * 256 + threadIdx.x;
    if (e >= E) return;
    // MASK = (1,1,0,0); mask = ind<2 ? 1 : 0
    float mask = (indp[0] < 2) ? 1.0f : 0.0f;
    int s = src[e];
    float v = (s == dst[e]) ? mask : 1.0f;
    atomicAdd(&degree[s], v);
}

// h = tanh(feat@W1 + b1) @ W2 + b2, per-block 64 rows.
// LDS: W (64KB) + A-tile (32KB). Each thread: 8 rows x 4 cols accumulators.
__global__ __launch_bounds__(256) void k_mlp(const float* __restrict__ feat,
                                             const float* __restrict__ W1,
                                             const float* __restrict__ b1,
                                             const float* __restrict__ W2,
                                             const float* __restrict__ b2,
                                             float* __restrict__ h, int n) {
    __shared__ float sW[D * D];     // 64 KB
    __shared__ float sA[64 * D];    // 32 KB
    const int t = threadIdx.x;
    const int row0 = blockIdx.x * 64;

    // stage W1
    {
        const float4* Wv = (const float4*)W1;
        float4* sWv = (float4*)sW;
        for (int i = t; i < D * D / 4; i += 256) sWv[i] = Wv[i];
    }
    // stage A tile (zero-fill OOB rows)
    {
        float4* sAv = (float4*)sA;
        for (int i = t; i < 64 * D / 4; i += 256) {
            int r = (i * 4) / D;
            int c = (i * 4) % D;
            int gr = row0 + r;
            float4 v = make_float4(0.f, 0.f, 0.f, 0.f);
            if (gr < n) v = *(const float4*)&feat[(size_t)gr * D + c];
            sAv[i] = v;
        }
    }
    __syncthreads();

    const int rbase = (t >> 5) * 8;   // 8 thread-groups of 32 -> 8 rows each
    const int cbase = (t & 31) * 4;   // 32 col-groups of 4

    float acc[8][4];
#pragma unroll
    for (int i = 0; i < 8; ++i)
#pragma unroll
        for (int j = 0; j < 4; ++j) acc[i][j] = 0.f;

    // GEMM1: acc = A @ W1
    for (int k = 0; k < D; k += 4) {
        float4 w0 = *(const float4*)&sW[(k + 0) * D + cbase];
        float4 w1 = *(const float4*)&sW[(k + 1) * D + cbase];
        float4 w2 = *(const float4*)&sW[(k + 2) * D + cbase];
        float4 w3 = *(const float4*)&sW[(k + 3) * D + cbase];
#pragma unroll
        for (int i = 0; i < 8; ++i) {
            float4 a = *(const float4*)&sA[(rbase + i) * D + k];
            acc[i][0] = fmaf(a.x, w0.x, acc[i][0]);
            acc[i][1] = fmaf(a.x, w0.y, acc[i][1]);
            acc[i][2] = fmaf(a.x, w0.z, acc[i][2]);
            acc[i][3] = fmaf(a.x, w0.w, acc[i][3]);
            acc[i][0] = fmaf(a.y, w1.x, acc[i][0]);
            acc[i][1] = fmaf(a.y, w1.y, acc[i][1]);
            acc[i][2] = fmaf(a.y, w1.z, acc[i][2]);
            acc[i][3] = fmaf(a.y, w1.w, acc[i][3]);
            acc[i][0] = fmaf(a.z, w2.x, acc[i][0]);
            acc[i][1] = fmaf(a.z, w2.y, acc[i][1]);
            acc[i][2] = fmaf(a.z, w2.z, acc[i][2]);
            acc[i][3] = fmaf(a.z, w2.w, acc[i][3]);
            acc[i][0] = fmaf(a.w, w3.x, acc[i][0]);
            acc[i][1] = fmaf(a.w, w3.y, acc[i][1]);
            acc[i][2] = fmaf(a.w, w3.z, acc[i][2]);
            acc[i][3] = fmaf(a.w, w3.w, acc[i][3]);
        }
    }

    float4 bb1 = *(const float4*)&b1[cbase];
    __syncthreads();  // everyone done reading sA/sW before overwrite

    // tanh -> sA; stage W2 -> sW
#pragma unroll
    for (int i = 0; i < 8; ++i) {
        float4 tv;
        tv.x = tanhf(acc[i][0] + bb1.x);
        tv.y = tanhf(acc[i][1] + bb1.y);
        tv.z = tanhf(acc[i][2] + bb1.z);
        tv.w = tanhf(acc[i][3] + bb1.w);
        *(float4*)&sA[(rbase + i) * D + cbase] = tv;
    }
    {
        const float4* Wv = (const float4*)W2;
        float4* sWv = (float4*)sW;
        for (int i = t; i < D * D / 4; i += 256) sWv[i] = Wv[i];
    }
    __syncthreads();

#pragma unroll
    for (int i = 0; i < 8; ++i)
#pragma unroll
        for (int j = 0; j < 4; ++j) acc[i][j] = 0.f;

    // GEMM2: acc = tanh(...) @ W2
    for (int k = 0; k < D; k += 4) {
        float4 w0 = *(const float4*)&sW[(k + 0) * D + cbase];
        float4 w1 = *(const float4*)&sW[(k + 1) * D + cbase];
        float4 w2 = *(const float4*)&sW[(k + 2) * D + cbase];
        float4 w3 = *(const float4*)&sW[(k + 3) * D + cbase];
#pragma unroll
        for (int i = 0; i < 8; ++i) {
            float4 a = *(const float4*)&sA[(rbase + i) * D + k];
            acc[i][0] = fmaf(a.x, w0.x, acc[i][0]);
            acc[i][1] = fmaf(a.x, w0.y, acc[i][1]);
            acc[i][2] = fmaf(a.x, w0.z, acc[i][2]);
            acc[i][3] = fmaf(a.x, w0.w, acc[i][3]);
            acc[i][0] = fmaf(a.y, w1.x, acc[i][0]);
            acc[i][1] = fmaf(a.y, w1.y, acc[i][1]);
            acc[i][2] = fmaf(a.y, w1.z, acc[i][2]);
            acc[i][3] = fmaf(a.y, w1.w, acc[i][3]);
            acc[i][0] = fmaf(a.z, w2.x, acc[i][0]);
            acc[i][1] = fmaf(a.z, w2.y, acc[i][1]);
            acc[i][2] = fmaf(a.z, w2.z, acc[i][2]);
            acc[i][3] = fmaf(a.z, w2.w, acc[i][3]);
            acc[i][0] = fmaf(a.w, w3.x, acc[i][0]);
            acc[i][1] = fmaf(a.w, w3.y, acc[i][1]);
            acc[i][2] = fmaf(a.w, w3.z, acc[i][2]);
            acc[i][3] = fmaf(a.w, w3.w, acc[i][3]);
        }
    }

    float4 bb2 = *(const float4*)&b2[cbase];
#pragma unroll
    for (int i = 0; i < 8; ++i) {
        int gr = row0 + rbase + i;
        if (gr < n) {
            float4 ov;
            ov.x = acc[i][0] + bb2.x;
            ov.y = acc[i][1] + bb2.y;
            ov.z = acc[i][2] + bb2.z;
            ov.w = acc[i][3] + bb2.w;
            *(float4*)&h[(size_t)gr * D + cbase] = ov;
        }
    }
}

// One wave per edge; lane handles 2 channels. results[src] += w*h[dst]; row_sum[src] += w.
__global__ __launch_bounds__(256) void k_scatter(const int* __restrict__ src,
                                                 const int* __restrict__ dst,
                                                 const float* __restrict__ W_edge,
                                                 const float* __restrict__ degree,
                                                 const float* __restrict__ h,
                                                 float* __restrict__ results,
                                                 float* __restrict__ row_sum, int E) {
    long long tid = (long long)blockIdx.x * 256 + threadIdx.x;
    int e = (int)(tid >> 6);
    int lane = (int)(tid & 63);
    if (e >= E) return;
    int s = src[e];
    int d = dst[e];
    float w = degree[d] * W_edge[e];
    if (lane == 0) atomicAdd(&row_sum[s], w);
    const float2 hv = *(const float2*)&h[(size_t)d * D + lane * 2];
    float* rp = &results[(size_t)s * D + lane * 2];
    atomicAdd(rp, w * hv.x);
    atomicAdd(rp + 1, w * hv.y);
}

__global__ __launch_bounds__(256) void k_div(float* __restrict__ out,
                                             const float* __restrict__ row_sum, int n) {
    int i = blockIdx.x * 256 + threadIdx.x;  // one float4 per thread
    int total = n * (D / 4);
    if (i >= total) return;
    int v = i / (D / 4);
    float rs = row_sum[v];
    rs = (rs == 0.f) ? 1.f : rs;
    float4* p = (float4*)out + i;
    float4 x = *p;
    x.x /= rs;
    x.y /= rs;
    x.z /= rs;
    x.w /= rs;
    *p = x;
}

extern "C" void kernel_launch(void* const* d_in, const int* in_sizes, int n_in,
                              void* d_out, int out_size, void* d_ws, size_t ws_size,
                              hipStream_t stream) {
    const float* feat   = (const float*)d_in[0];
    const float* W_edge = (const float*)d_in[1];
    const float* W1     = (const float*)d_in[2];
    const float* b1     = (const float*)d_in[3];
    const float* W2     = (const float*)d_in[4];
    const float* b2     = (const float*)d_in[5];
    const int* edge_src = (const int*)d_in[6];
    const int* edge_dst = (const int*)d_in[7];
    const int* indp     = (const int*)d_in[8];

    const int n = in_sizes[0] / D;   // 100000
    const int E = in_sizes[6];       // 600000

    // ws layout: degree[n] | row_sum[n] | h[n*D]
    float* degree  = (float*)d_ws;
    float* row_sum = degree + n;
    float* h       = row_sum + n;
    float* out     = (float*)d_out;

    hipMemsetAsync(degree, 0, (size_t)2 * n * sizeof(float), stream);
    hipMemsetAsync(d_out, 0, (size_t)out_size * sizeof(float), stream);

    k_degree<<<(E + 255) / 256, 256, 0, stream>>>(edge_src, edge_dst, indp, degree, E);
    k_mlp<<<(n + 63) / 64, 256, 0, stream>>>(feat, W1, b1, W2, b2, h, n);

    long long sthreads = (long long)E * 64;
    k_scatter<<<(int)((sthreads + 255) / 256), 256, 0, stream>>>(edge_src, edge_dst, W_edge,
                                                                 degree, h, out, row_sum, E);

    int dthreads = n * (D / 4);
    k_div<<<(dthreads + 255) / 256, 256, 0, stream>>>(out, row_sum, n);
}

// Round 2
// 357.823 us; speedup vs baseline: 2.1689x; 2.1689x over previous
//
#include <hip/hip_runtime.h>

// MeanAggregator on MI355X.
// Stages: degree+count -> scan (CSR row_ptr) -> place (sorted edges, w precomputed)
//         -> MLP (f32 LDS GEMM) -> per-node gather aggregate (no atomics) .

constexpr int D = 128;
constexpr int SCAN_CHUNK = 1024;  // elements per scan block (256 thr x 4)

// Pass 1: degree[s] += value, count[s] += 1
__global__ __launch_bounds__(256) void k_degree_count(const int* __restrict__ src,
                                                      const int* __restrict__ dst,
                                                      const int* __restrict__ indp,
                                                      float* __restrict__ degree,
                                                      int* __restrict__ count, int E) {
    int e = blockIdx.x * 256 + threadIdx.x;
    if (e >= E) return;
    float mask = (indp[0] < 2) ? 1.0f : 0.0f;  // MASK = (1,1,0,0)
    int s = src[e];
    float v = (s == dst[e]) ? mask : 1.0f;
    atomicAdd(&degree[s], v);
    atomicAdd(&count[s], 1);
}

// Scan stage 1: per-block (1024 elems) exclusive scan; block total -> block_sums
__global__ __launch_bounds__(256) void k_scan_local(const int* __restrict__ count,
                                                    int* __restrict__ row_ptr,
                                                    int* __restrict__ block_sums, int n) {
    __shared__ int s[256];
    const int t = threadIdx.x;
    const int base = blockIdx.x * SCAN_CHUNK + t * 4;
    int v0 = (base + 0 < n) ? count[base + 0] : 0;
    int v1 = (base + 1 < n) ? count[base + 1] : 0;
    int v2 = (base + 2 < n) ? count[base + 2] : 0;
    int v3 = (base + 3 < n) ? count[base + 3] : 0;
    int sum4 = v0 + v1 + v2 + v3;
    s[t] = sum4;
    __syncthreads();
#pragma unroll
    for (int off = 1; off < 256; off <<= 1) {
        int x = (t >= off) ? s[t - off] : 0;
        __syncthreads();
        s[t] += x;
        __syncthreads();
    }
    int excl = s[t] - sum4;
    if (t == 255) block_sums[blockIdx.x] = s[255];
    if (base + 0 < n) row_ptr[base + 0] = excl;
    excl += v0;
    if (base + 1 < n) row_ptr[base + 1] = excl;
    excl += v1;
    if (base + 2 < n) row_ptr[base + 2] = excl;
    excl += v2;
    if (base + 3 < n) row_ptr[base + 3] = excl;
}

// Scan stage 2: single block, exclusive-scan the block sums; total -> row_ptr[n]
__global__ __launch_bounds__(128) void k_scan_blocks(int* __restrict__ block_sums,
                                                     int* __restrict__ row_ptr,
                                                     int nb, int n) {
    __shared__ int s[128];
    const int t = threadIdx.x;
    int v = (t < nb) ? block_sums[t] : 0;
    s[t] = v;
    __syncthreads();
#pragma unroll
    for (int off = 1; off < 128; off <<= 1) {
        int x = (t >= off) ? s[t - off] : 0;
        __syncthreads();
        s[t] += x;
        __syncthreads();
    }
    if (t < nb) block_sums[t] = s[t] - v;  // exclusive
    if (t == 127) row_ptr[n] = s[127];     // grand total (== E)
}

// Scan stage 3: add block offsets
__global__ __launch_bounds__(256) void k_scan_add(int* __restrict__ row_ptr,
                                                  const int* __restrict__ block_sums, int n) {
    const int t = threadIdx.x;
    const int base = blockIdx.x * SCAN_CHUNK + t * 4;
    const int off = block_sums[blockIdx.x];
#pragma unroll
    for (int j = 0; j < 4; ++j)
        if (base + j < n) row_ptr[base + j] += off;
}

// Place edges into CSR order; precompute w = degree[dst] * W_edge
__global__ __launch_bounds__(256) void k_place(const int* __restrict__ src,
                                               const int* __restrict__ dst,
                                               const float* __restrict__ W_edge,
                                               const float* __restrict__ degree,
                                               const int* __restrict__ row_ptr,
                                               int* __restrict__ cursor,
                                               int* __restrict__ dst_sorted,
                                               float* __restrict__ w_sorted, int E) {
    int e = blockIdx.x * 256 + threadIdx.x;
    if (e >= E) return;
    int s = src[e];
    int d = dst[e];
    int pos = row_ptr[s] + atomicAdd(&cursor[s], 1);
    dst_sorted[pos] = d;
    w_sorted[pos] = degree[d] * W_edge[e];
}

// h = tanh(feat@W1 + b1) @ W2 + b2, per-block 64 rows (f32, LDS-staged).
__global__ __launch_bounds__(256) void k_mlp(const float* __restrict__ feat,
                                             const float* __restrict__ W1,
                                             const float* __restrict__ b1,
                                             const float* __restrict__ W2,
                                             const float* __restrict__ b2,
                                             float* __restrict__ h, int n) {
    __shared__ float sW[D * D];
    __shared__ float sA[64 * D];
    const int t = threadIdx.x;
    const int row0 = blockIdx.x * 64;

    {
        const float4* Wv = (const float4*)W1;
        float4* sWv = (float4*)sW;
        for (int i = t; i < D * D / 4; i += 256) sWv[i] = Wv[i];
    }
    {
        float4* sAv = (float4*)sA;
        for (int i = t; i < 64 * D / 4; i += 256) {
            int r = (i * 4) / D;
            int c = (i * 4) % D;
            int gr = row0 + r;
            float4 v = make_float4(0.f, 0.f, 0.f, 0.f);
            if (gr < n) v = *(const float4*)&feat[(size_t)gr * D + c];
            sAv[i] = v;
        }
    }
    __syncthreads();

    const int rbase = (t >> 5) * 8;
    const int cbase = (t & 31) * 4;

    float acc[8][4];
#pragma unroll
    for (int i = 0; i < 8; ++i)
#pragma unroll
        for (int j = 0; j < 4; ++j) acc[i][j] = 0.f;

    for (int k = 0; k < D; k += 4) {
        float4 w0 = *(const float4*)&sW[(k + 0) * D + cbase];
        float4 w1 = *(const float4*)&sW[(k + 1) * D + cbase];
        float4 w2 = *(const float4*)&sW[(k + 2) * D + cbase];
        float4 w3 = *(const float4*)&sW[(k + 3) * D + cbase];
#pragma unroll
        for (int i = 0; i < 8; ++i) {
            float4 a = *(const float4*)&sA[(rbase + i) * D + k];
            acc[i][0] = fmaf(a.x, w0.x, acc[i][0]);
            acc[i][1] = fmaf(a.x, w0.y, acc[i][1]);
            acc[i][2] = fmaf(a.x, w0.z, acc[i][2]);
            acc[i][3] = fmaf(a.x, w0.w, acc[i][3]);
            acc[i][0] = fmaf(a.y, w1.x, acc[i][0]);
            acc[i][1] = fmaf(a.y, w1.y, acc[i][1]);
            acc[i][2] = fmaf(a.y, w1.z, acc[i][2]);
            acc[i][3] = fmaf(a.y, w1.w, acc[i][3]);
            acc[i][0] = fmaf(a.z, w2.x, acc[i][0]);
            acc[i][1] = fmaf(a.z, w2.y, acc[i][1]);
            acc[i][2] = fmaf(a.z, w2.z, acc[i][2]);
            acc[i][3] = fmaf(a.z, w2.w, acc[i][3]);
            acc[i][0] = fmaf(a.w, w3.x, acc[i][0]);
            acc[i][1] = fmaf(a.w, w3.y, acc[i][1]);
            acc[i][2] = fmaf(a.w, w3.z, acc[i][2]);
            acc[i][3] = fmaf(a.w, w3.w, acc[i][3]);
        }
    }

    float4 bb1 = *(const float4*)&b1[cbase];
    __syncthreads();

#pragma unroll
    for (int i = 0; i < 8; ++i) {
        float4 tv;
        tv.x = tanhf(acc[i][0] + bb1.x);
        tv.y = tanhf(acc[i][1] + bb1.y);
        tv.z = tanhf(acc[i][2] + bb1.z);
        tv.w = tanhf(acc[i][3] + bb1.w);
        *(float4*)&sA[(rbase + i) * D + cbase] = tv;
    }
    {
        const float4* Wv = (const float4*)W2;
        float4* sWv = (float4*)sW;
        for (int i = t; i < D * D / 4; i += 256) sWv[i] = Wv[i];
    }
    __syncthreads();

#pragma unroll
    for (int i = 0; i < 8; ++i)
#pragma unroll
        for (int j = 0; j < 4; ++j) acc[i][j] = 0.f;

    for (int k = 0; k < D; k += 4) {
        float4 w0 = *(const float4*)&sW[(k + 0) * D + cbase];
        float4 w1 = *(const float4*)&sW[(k + 1) * D + cbase];
        float4 w2 = *(const float4*)&sW[(k + 2) * D + cbase];
        float4 w3 = *(const float4*)&sW[(k + 3) * D + cbase];
#pragma unroll
        for (int i = 0; i < 8; ++i) {
            float4 a = *(const float4*)&sA[(rbase + i) * D + k];
            acc[i][0] = fmaf(a.x, w0.x, acc[i][0]);
            acc[i][1] = fmaf(a.x, w0.y, acc[i][1]);
            acc[i][2] = fmaf(a.x, w0.z, acc[i][2]);
            acc[i][3] = fmaf(a.x, w0.w, acc[i][3]);
            acc[i][0] = fmaf(a.y, w1.x, acc[i][0]);
            acc[i][1] = fmaf(a.y, w1.y, acc[i][1]);
            acc[i][2] = fmaf(a.y, w1.z, acc[i][2]);
            acc[i][3] = fmaf(a.y, w1.w, acc[i][3]);
            acc[i][0] = fmaf(a.z, w2.x, acc[i][0]);
            acc[i][1] = fmaf(a.z, w2.y, acc[i][1]);
            acc[i][2] = fmaf(a.z, w2.z, acc[i][2]);
            acc[i][3] = fmaf(a.z, w2.w, acc[i][3]);
            acc[i][0] = fmaf(a.w, w3.x, acc[i][0]);
            acc[i][1] = fmaf(a.w, w3.y, acc[i][1]);
            acc[i][2] = fmaf(a.w, w3.z, acc[i][2]);
            acc[i][3] = fmaf(a.w, w3.w, acc[i][3]);
        }
    }

    float4 bb2 = *(const float4*)&b2[cbase];
#pragma unroll
    for (int i = 0; i < 8; ++i) {
        int gr = row0 + rbase + i;
        if (gr < n) {
            float4 ov;
            ov.x = acc[i][0] + bb2.x;
            ov.y = acc[i][1] + bb2.y;
            ov.z = acc[i][2] + bb2.z;
            ov.w = acc[i][3] + bb2.w;
            *(float4*)&h[(size_t)gr * D + cbase] = ov;
        }
    }
}

// One wave per node: gather w*h[dst] over the node's CSR range, divide, store.
__global__ __launch_bounds__(256) void k_aggregate(const int* __restrict__ row_ptr,
                                                   const int* __restrict__ dst_sorted,
                                                   const float* __restrict__ w_sorted,
                                                   const float* __restrict__ h,
                                                   float* __restrict__ out, int n) {
    long long tid = (long long)blockIdx.x * 256 + threadIdx.x;
    int v = (int)(tid >> 6);
    int lane = (int)(tid & 63);
    if (v >= n) return;
    int beg = row_ptr[v];
    int end = row_ptr[v + 1];
    float ax = 0.f, ay = 0.f, rs = 0.f;
    for (int i = beg; i < end; ++i) {
        int d = dst_sorted[i];
        float w = w_sorted[i];
        rs += w;
        const float2 hv = *(const float2*)&h[(size_t)d * D + lane * 2];
        ax = fmaf(w, hv.x, ax);
        ay = fmaf(w, hv.y, ay);
    }
    rs = (rs == 0.f) ? 1.f : rs;
    float2 o;
    o.x = ax / rs;
    o.y = ay / rs;
    *(float2*)&out[(size_t)v * D + lane * 2] = o;
}

extern "C" void kernel_launch(void* const* d_in, const int* in_sizes, int n_in,
                              void* d_out, int out_size, void* d_ws, size_t ws_size,
                              hipStream_t stream) {
    const float* feat   = (const float*)d_in[0];
    const float* W_edge = (const float*)d_in[1];
    const float* W1     = (const float*)d_in[2];
    const float* b1     = (const float*)d_in[3];
    const float* W2     = (const float*)d_in[4];
    const float* b2     = (const float*)d_in[5];
    const int* edge_src = (const int*)d_in[6];
    const int* edge_dst = (const int*)d_in[7];
    const int* indp     = (const int*)d_in[8];

    const int n = in_sizes[0] / D;   // 100000
    const int E = in_sizes[6];       // 600000
    const int nb = (n + SCAN_CHUNK - 1) / SCAN_CHUNK;  // scan blocks (98)

    // ws layout: degree[n] f | count[n] i | cursor[n] i | row_ptr[n+1] i |
    //            block_sums[nb(pad 128)] i | dst_sorted[E] i | w_sorted[E] f | h[n*D] f
    float* degree     = (float*)d_ws;
    int*   count      = (int*)(degree + n);
    int*   cursor     = count + n;
    int*   row_ptr    = cursor + n;
    int*   block_sums = row_ptr + n + 1;
    int*   dst_sorted = block_sums + 128;
    float* w_sorted   = (float*)(dst_sorted + E);
    float* h          = w_sorted + E;

    // zero degree+count+cursor (contiguous)
    hipMemsetAsync(degree, 0, (size_t)3 * n * sizeof(float), stream);

    const int eb = (E + 255) / 256;
    k_degree_count<<<eb, 256, 0, stream>>>(edge_src, edge_dst, indp, degree, count, E);
    k_scan_local<<<nb, 256, 0, stream>>>(count, row_ptr, block_sums, n);
    k_scan_blocks<<<1, 128, 0, stream>>>(block_sums, row_ptr, nb, n);
    k_scan_add<<<nb, 256, 0, stream>>>(row_ptr, block_sums, n);
    k_place<<<eb, 256, 0, stream>>>(edge_src, edge_dst, W_edge, degree, row_ptr, cursor,
                                    dst_sorted, w_sorted, E);

    k_mlp<<<(n + 63) / 64, 256, 0, stream>>>(feat, W1, b1, W2, b2, h, n);

    long long athreads = (long long)n * 64;
    k_aggregate<<<(int)((athreads + 255) / 256), 256, 0, stream>>>(row_ptr, dst_sorted,
                                                                   w_sorted, h,
                                                                   (float*)d_out, n);
}

// Round 3
// 186.969 us; speedup vs baseline: 4.1508x; 1.9138x over previous
//
#include <hip/hip_runtime.h>

// MeanAggregator on MI355X.
// prep (W->bf16 transposed) -> count -> scan (CSR row_ptr + degree) -> place (pairs)
// -> MLP (bf16 MFMA, swizzled LDS) -> per-node gather aggregate.

constexpr int D = 128;
constexpr int SCAN_CHUNK = 1024;

typedef __attribute__((ext_vector_type(8))) short short8;
typedef __attribute__((ext_vector_type(4))) float f32x4;
struct ushort8_s { unsigned short v[8]; };

__device__ __forceinline__ unsigned short f2bf(float x) {
    unsigned int u = __float_as_uint(x);
    u += 0x7fffu + ((u >> 16) & 1u);
    return (unsigned short)(u >> 16);
}

// ---- W transpose+convert: Wt[n*D+k] = bf16(W[k*D+n]) ----
__global__ __launch_bounds__(256) void k_prep(const float* __restrict__ W1,
                                              const float* __restrict__ W2,
                                              unsigned short* __restrict__ Wt1,
                                              unsigned short* __restrict__ Wt2) {
    int t = blockIdx.x * 256 + threadIdx.x;
    if (t >= D * D) return;
    int k = t >> 7, nn = t & 127;  // coalesced read at index t = k*D+n
    Wt1[nn * D + k] = f2bf(W1[t]);
    Wt2[nn * D + k] = f2bf(W2[t]);
}

// ---- per-src edge count (+ rare self-loop count) ----
__global__ __launch_bounds__(256) void k_count(const int* __restrict__ src,
                                               const int* __restrict__ dst,
                                               int* __restrict__ count,
                                               int* __restrict__ selfc, int E) {
    int e = blockIdx.x * 256 + threadIdx.x;
    if (e >= E) return;
    int s = src[e];
    atomicAdd(&count[s], 1);
    if (s == dst[e]) atomicAdd(&selfc[s], 1);
}

// ---- scan stage 1: local exclusive scan; also degree = count - (1-mask)*self; count->0 ----
__global__ __launch_bounds__(256) void k_scan_local(int* __restrict__ count,
                                                    const int* __restrict__ selfc,
                                                    const int* __restrict__ indp,
                                                    float* __restrict__ degree,
                                                    int* __restrict__ row_ptr,
                                                    int* __restrict__ block_sums, int n) {
    __shared__ int s[256];
    const int t = threadIdx.x;
    const int base = blockIdx.x * SCAN_CHUNK + t * 4;
    const float mask = (indp[0] < 2) ? 1.0f : 0.0f;  // MASK = (1,1,0,0)
    int v[4];
#pragma unroll
    for (int j = 0; j < 4; ++j) {
        v[j] = 0;
        if (base + j < n) {
            int c = count[base + j];
            v[j] = c;
            degree[base + j] = (float)c + (mask - 1.0f) * (float)selfc[base + j];
            count[base + j] = 0;  // becomes place's cursor
        }
    }
    int sum4 = v[0] + v[1] + v[2] + v[3];
    s[t] = sum4;
    __syncthreads();
#pragma unroll
    for (int off = 1; off < 256; off <<= 1) {
        int x = (t >= off) ? s[t - off] : 0;
        __syncthreads();
        s[t] += x;
        __syncthreads();
    }
    int excl = s[t] - sum4;
    if (t == 255) block_sums[blockIdx.x] = s[255];
#pragma unroll
    for (int j = 0; j < 4; ++j) {
        if (base + j < n) row_ptr[base + j] = excl;
        excl += v[j];
    }
}

__global__ __launch_bounds__(128) void k_scan_blocks(int* __restrict__ block_sums,
                                                     int* __restrict__ row_ptr,
                                                     int nb, int n) {
    __shared__ int s[128];
    const int t = threadIdx.x;
    int v = (t < nb) ? block_sums[t] : 0;
    s[t] = v;
    __syncthreads();
#pragma unroll
    for (int off = 1; off < 128; off <<= 1) {
        int x = (t >= off) ? s[t - off] : 0;
        __syncthreads();
        s[t] += x;
        __syncthreads();
    }
    if (t < nb) block_sums[t] = s[t] - v;
    if (t == 127) row_ptr[n] = s[127];
}

__global__ __launch_bounds__(256) void k_scan_add(int* __restrict__ row_ptr,
                                                  const int* __restrict__ block_sums, int n) {
    const int t = threadIdx.x;
    const int base = blockIdx.x * SCAN_CHUNK + t * 4;
    const int off = block_sums[blockIdx.x];
#pragma unroll
    for (int j = 0; j < 4; ++j)
        if (base + j < n) row_ptr[base + j] += off;
}

// ---- place: pairs[pos] = (dst, degree[dst]*W_edge[e]) in CSR-by-src order ----
__global__ __launch_bounds__(256) void k_place(const int* __restrict__ src,
                                               const int* __restrict__ dst,
                                               const float* __restrict__ W_edge,
                                               const float* __restrict__ degree,
                                               const int* __restrict__ row_ptr,
                                               int* __restrict__ cursor,
                                               float2* __restrict__ pairs, int E) {
    int e = blockIdx.x * 256 + threadIdx.x;
    if (e >= E) return;
    int s = src[e];
    int d = dst[e];
    int pos = row_ptr[s] + atomicAdd(&cursor[s], 1);
    float2 p;
    p.x = __int_as_float(d);
    p.y = degree[d] * W_edge[e];
    pairs[pos] = p;
}

// ---- MLP: h = bf16( tanh(feat@W1+b1) @ W2 + b2 ), MFMA bf16, swizzled LDS ----
__global__ __launch_bounds__(256) void k_mlp(const float* __restrict__ feat,
                                             const unsigned short* __restrict__ Wt1,
                                             const unsigned short* __restrict__ Wt2,
                                             const float* __restrict__ b1,
                                             const float* __restrict__ b2,
                                             unsigned short* __restrict__ hbf, int n) {
    __shared__ unsigned short sA[128 * D];  // 32 KB, rows of A / tanh / h (swizzled)
    __shared__ unsigned short sW[D * D];    // 32 KB, Wt rows [n][k]    (swizzled)
    const int t = threadIdx.x;
    const int lane = t & 63;
    const int row0 = blockIdx.x * 128;
    const int r0w = (t >> 6) * 32;  // this wave's 32 rows

    // stage A tile: feat f32 -> bf16, swizzled 16B chunks
    for (int c = t; c < 2048; c += 256) {
        int r = c >> 4, k0 = (c & 15) * 8;
        int gr = row0 + r;
        ushort8_s v;
        if (gr < n) {
            const float4 f0 = *(const float4*)&feat[(size_t)gr * D + k0];
            const float4 f1 = *(const float4*)&feat[(size_t)gr * D + k0 + 4];
            v.v[0] = f2bf(f0.x); v.v[1] = f2bf(f0.y); v.v[2] = f2bf(f0.z); v.v[3] = f2bf(f0.w);
            v.v[4] = f2bf(f1.x); v.v[5] = f2bf(f1.y); v.v[6] = f2bf(f1.z); v.v[7] = f2bf(f1.w);
        } else {
#pragma unroll
            for (int j = 0; j < 8; ++j) v.v[j] = 0;
        }
        *(ushort8_s*)((char*)sA + ((r * 256 + k0 * 2) ^ ((r & 7) << 4))) = v;
    }
    // stage Wt1 (already bf16, [n][k] row-major)
    for (int c = t; c < 2048; c += 256) {
        int r = c >> 4, k0 = (c & 15) * 8;
        ushort8_s v = *(const ushort8_s*)&Wt1[c * 8];
        *(ushort8_s*)((char*)sW + ((r * 256 + k0 * 2) ^ ((r & 7) << 4))) = v;
    }
    __syncthreads();

    f32x4 acc[2][8];
#pragma unroll
    for (int rf = 0; rf < 2; ++rf)
#pragma unroll
        for (int nf = 0; nf < 8; ++nf) acc[rf][nf] = (f32x4){0.f, 0.f, 0.f, 0.f};

    // GEMM1
#pragma unroll
    for (int kc = 0; kc < 4; ++kc) {
        const int kb = (kc * 32 + (lane >> 4) * 8) * 2;
        const int ra0 = r0w + (lane & 15);
        const int ra1 = ra0 + 16;
        short8 a0 = *(short8*)((char*)sA + ((ra0 * 256 + kb) ^ ((ra0 & 7) << 4)));
        short8 a1 = *(short8*)((char*)sA + ((ra1 * 256 + kb) ^ ((ra1 & 7) << 4)));
#pragma unroll
        for (int nf = 0; nf < 8; ++nf) {
            const int rb = nf * 16 + (lane & 15);
            short8 b = *(short8*)((char*)sW + ((rb * 256 + kb) ^ ((rb & 7) << 4)));
            acc[0][nf] = __builtin_amdgcn_mfma_f32_16x16x32_bf16(a0, b, acc[0][nf], 0, 0, 0);
            acc[1][nf] = __builtin_amdgcn_mfma_f32_16x16x32_bf16(a1, b, acc[1][nf], 0, 0, 0);
        }
    }
    __syncthreads();  // all waves done reading sW/sA

    // tanh -> sA (this wave's own rows only); restage sW = Wt2
#pragma unroll
    for (int rf = 0; rf < 2; ++rf)
#pragma unroll
        for (int nf = 0; nf < 8; ++nf) {
            const int col = nf * 16 + (lane & 15);
            const float bias = b1[col];
#pragma unroll
            for (int i = 0; i < 4; ++i) {
                const int row = r0w + rf * 16 + (lane >> 4) * 4 + i;
                unsigned short hv = f2bf(tanhf(acc[rf][nf][i] + bias));
                *(unsigned short*)((char*)sA + ((row * 256 + col * 2) ^ ((row & 7) << 4))) = hv;
            }
        }
    for (int c = t; c < 2048; c += 256) {
        int r = c >> 4, k0 = (c & 15) * 8;
        ushort8_s v = *(const ushort8_s*)&Wt2[c * 8];
        *(ushort8_s*)((char*)sW + ((r * 256 + k0 * 2) ^ ((r & 7) << 4))) = v;
    }
    __syncthreads();

#pragma unroll
    for (int rf = 0; rf < 2; ++rf)
#pragma unroll
        for (int nf = 0; nf < 8; ++nf) acc[rf][nf] = (f32x4){0.f, 0.f, 0.f, 0.f};

    // GEMM2
#pragma unroll
    for (int kc = 0; kc < 4; ++kc) {
        const int kb = (kc * 32 + (lane >> 4) * 8) * 2;
        const int ra0 = r0w + (lane & 15);
        const int ra1 = ra0 + 16;
        short8 a0 = *(short8*)((char*)sA + ((ra0 * 256 + kb) ^ ((ra0 & 7) << 4)));
        short8 a1 = *(short8*)((char*)sA + ((ra1 * 256 + kb) ^ ((ra1 & 7) << 4)));
#pragma unroll
        for (int nf = 0; nf < 8; ++nf) {
            const int rb = nf * 16 + (lane & 15);
            short8 b = *(short8*)((char*)sW + ((rb * 256 + kb) ^ ((rb & 7) << 4)));
            acc[0][nf] = __builtin_amdgcn_mfma_f32_16x16x32_bf16(a0, b, acc[0][nf], 0, 0, 0);
            acc[1][nf] = __builtin_amdgcn_mfma_f32_16x16x32_bf16(a1, b, acc[1][nf], 0, 0, 0);
        }
    }

    // epilogue: +b2 -> bf16 -> sA (own rows; own reads already done)
#pragma unroll
    for (int rf = 0; rf < 2; ++rf)
#pragma unroll
        for (int nf = 0; nf < 8; ++nf) {
            const int col = nf * 16 + (lane & 15);
            const float bias = b2[col];
#pragma unroll
            for (int i = 0; i < 4; ++i) {
                const int row = r0w + rf * 16 + (lane >> 4) * 4 + i;
                unsigned short hv = f2bf(acc[rf][nf][i] + bias);
                *(unsigned short*)((char*)sA + ((row * 256 + col * 2) ^ ((row & 7) << 4))) = hv;
            }
        }
    __syncthreads();

    // coalesced store h (bf16)
    for (int c = t; c < 2048; c += 256) {
        int r = c >> 4, k0 = (c & 15) * 8;
        int gr = row0 + r;
        if (gr < n) {
            ushort8_s v = *(ushort8_s*)((char*)sA + ((r * 256 + k0 * 2) ^ ((r & 7) << 4)));
            *(ushort8_s*)&hbf[(size_t)gr * D + k0] = v;
        }
    }
}

// ---- aggregate: one wave per node, gather w*h[dst], divide, store f32 ----
__global__ __launch_bounds__(256) void k_aggregate(const int* __restrict__ row_ptr,
                                                   const float2* __restrict__ pairs,
                                                   const unsigned short* __restrict__ hbf,
                                                   float* __restrict__ out, int n) {
    long long tid = (long long)blockIdx.x * 256 + threadIdx.x;
    int v = (int)(tid >> 6);
    int lane = (int)(tid & 63);
    if (v >= n) return;
    int beg = row_ptr[v];
    int end = row_ptr[v + 1];
    float ax = 0.f, ay = 0.f, rs = 0.f;
    for (int i = beg; i < end; ++i) {
        float2 p = pairs[i];
        int d = __float_as_int(p.x);
        float w = p.y;
        rs += w;
        unsigned int hv = *(const unsigned int*)&hbf[(size_t)d * D + lane * 2];
        float h0 = __uint_as_float((hv & 0xffffu) << 16);
        float h1 = __uint_as_float(hv & 0xffff0000u);
        ax = fmaf(w, h0, ax);
        ay = fmaf(w, h1, ay);
    }
    rs = (rs == 0.f) ? 1.f : rs;
    float2 o;
    o.x = ax / rs;
    o.y = ay / rs;
    *(float2*)&out[(size_t)v * D + lane * 2] = o;
}

extern "C" void kernel_launch(void* const* d_in, const int* in_sizes, int n_in,
                              void* d_out, int out_size, void* d_ws, size_t ws_size,
                              hipStream_t stream) {
    const float* feat   = (const float*)d_in[0];
    const float* W_edge = (const float*)d_in[1];
    const float* W1     = (const float*)d_in[2];
    const float* b1     = (const float*)d_in[3];
    const float* W2     = (const float*)d_in[4];
    const float* b2     = (const float*)d_in[5];
    const int* edge_src = (const int*)d_in[6];
    const int* edge_dst = (const int*)d_in[7];
    const int* indp     = (const int*)d_in[8];

    const int n = in_sizes[0] / D;   // 100000
    const int E = in_sizes[6];       // 600000
    const int nb = (n + SCAN_CHUNK - 1) / SCAN_CHUNK;

    // ws: count[n] | selfc[n] | row_ptr[n+1] | block_sums[128] | degree[n] |
    //     Wt1[D*D] u16 | Wt2[D*D] u16 | (align16) pairs[E] f2 | hbf[n*D] u16
    char* ws = (char*)d_ws;
    int*   count      = (int*)ws;
    int*   selfc      = count + n;
    int*   row_ptr    = selfc + n;
    int*   block_sums = row_ptr + (n + 1);
    float* degree     = (float*)(block_sums + 128);
    unsigned short* Wt1 = (unsigned short*)(degree + n);
    unsigned short* Wt2 = Wt1 + D * D;
    size_t off = (size_t)((char*)(Wt2 + D * D) - ws);
    off = (off + 15) & ~(size_t)15;
    float2* pairs = (float2*)(ws + off);
    unsigned short* hbf = (unsigned short*)(pairs + E);

    hipMemsetAsync(count, 0, (size_t)2 * n * sizeof(int), stream);  // count+selfc

    const int eb = (E + 255) / 256;
    k_prep<<<(D * D + 255) / 256, 256, 0, stream>>>(W1, W2, Wt1, Wt2);
    k_count<<<eb, 256, 0, stream>>>(edge_src, edge_dst, count, selfc, E);
    k_scan_local<<<nb, 256, 0, stream>>>(count, selfc, indp, degree, row_ptr, block_sums, n);
    k_scan_blocks<<<1, 128, 0, stream>>>(block_sums, row_ptr, nb, n);
    k_scan_add<<<nb, 256, 0, stream>>>(row_ptr, block_sums, n);
    k_place<<<eb, 256, 0, stream>>>(edge_src, edge_dst, W_edge, degree, row_ptr, count,
                                    pairs, E);

    k_mlp<<<(n + 127) / 128, 256, 0, stream>>>(feat, Wt1, Wt2, b1, b2, hbf, n);

    long long athreads = (long long)n * 64;
    k_aggregate<<<(int)((athreads + 255) / 256), 256, 0, stream>>>(row_ptr, pairs, hbf,
                                                                   (float*)d_out, n);
}

// Round 4
// 139.118 us; speedup vs baseline: 5.5785x; 1.3440x over previous
//
#include <hip/hip_runtime.h>

// MeanAggregator on MI355X.
// prep+zero -> [mlp|count fused] -> scan_local -> scan_blocks -> place -> aggregate.

constexpr int D = 128;
constexpr int SCAN_CHUNK = 1024;

typedef __attribute__((ext_vector_type(8))) short short8;
typedef __attribute__((ext_vector_type(4))) float f32x4;
struct ushort8_s { unsigned short v[8]; };

__device__ __forceinline__ unsigned short f2bf(float x) {
    unsigned int u = __float_as_uint(x);
    u += 0x7fffu + ((u >> 16) & 1u);
    return (unsigned short)(u >> 16);
}
__device__ __forceinline__ float bflo(unsigned int u) { return __uint_as_float(u << 16); }
__device__ __forceinline__ float bfhi(unsigned int u) { return __uint_as_float(u & 0xffff0000u); }

// ---- prep: W transpose->bf16 (blocks 0..63) + zero count/selfc (rest) ----
__global__ __launch_bounds__(256) void k_prep(const float* __restrict__ W1,
                                              const float* __restrict__ W2,
                                              unsigned short* __restrict__ Wt1,
                                              unsigned short* __restrict__ Wt2,
                                              int* __restrict__ zbase, int zv4) {
    int b = blockIdx.x;
    if (b < 64) {
        int t = b * 256 + threadIdx.x;  // t = k*D+n, coalesced read
        int k = t >> 7, nn = t & 127;
        Wt1[nn * D + k] = f2bf(W1[t]);
        Wt2[nn * D + k] = f2bf(W2[t]);
    } else {
        int i = (b - 64) * 256 + threadIdx.x;
        if (i < zv4) ((int4*)zbase)[i] = make_int4(0, 0, 0, 0);
    }
}

// ---- fused: MLP (blocks < nm) | edge count (blocks >= nm) ----
__global__ __launch_bounds__(256) void k_mlp_count(const float* __restrict__ feat,
                                                   const unsigned short* __restrict__ Wt1,
                                                   const unsigned short* __restrict__ Wt2,
                                                   const float* __restrict__ b1,
                                                   const float* __restrict__ b2,
                                                   unsigned short* __restrict__ hbf, int n,
                                                   const int* __restrict__ src,
                                                   const int* __restrict__ dst,
                                                   int* __restrict__ count,
                                                   int* __restrict__ selfc, int E, int nm) {
    __shared__ unsigned short sA[128 * D];
    __shared__ unsigned short sW[D * D];
    if (blockIdx.x >= nm) {
        int e = (blockIdx.x - nm) * 256 + threadIdx.x;
        if (e < E) {
            int s = src[e];
            atomicAdd(&count[s], 1);
            if (s == dst[e]) atomicAdd(&selfc[s], 1);
        }
        return;
    }
    const int t = threadIdx.x;
    const int lane = t & 63;
    const int row0 = blockIdx.x * 128;
    const int r0w = (t >> 6) * 32;

    for (int c = t; c < 2048; c += 256) {
        int r = c >> 4, k0 = (c & 15) * 8;
        int gr = row0 + r;
        ushort8_s v;
        if (gr < n) {
            const float4 f0 = *(const float4*)&feat[(size_t)gr * D + k0];
            const float4 f1 = *(const float4*)&feat[(size_t)gr * D + k0 + 4];
            v.v[0] = f2bf(f0.x); v.v[1] = f2bf(f0.y); v.v[2] = f2bf(f0.z); v.v[3] = f2bf(f0.w);
            v.v[4] = f2bf(f1.x); v.v[5] = f2bf(f1.y); v.v[6] = f2bf(f1.z); v.v[7] = f2bf(f1.w);
        } else {
#pragma unroll
            for (int j = 0; j < 8; ++j) v.v[j] = 0;
        }
        *(ushort8_s*)((char*)sA + ((r * 256 + k0 * 2) ^ ((r & 7) << 4))) = v;
    }
    for (int c = t; c < 2048; c += 256) {
        int r = c >> 4, k0 = (c & 15) * 8;
        ushort8_s v = *(const ushort8_s*)&Wt1[c * 8];
        *(ushort8_s*)((char*)sW + ((r * 256 + k0 * 2) ^ ((r & 7) << 4))) = v;
    }
    __syncthreads();

    f32x4 acc[2][8];
#pragma unroll
    for (int rf = 0; rf < 2; ++rf)
#pragma unroll
        for (int nf = 0; nf < 8; ++nf) acc[rf][nf] = (f32x4){0.f, 0.f, 0.f, 0.f};

#pragma unroll
    for (int kc = 0; kc < 4; ++kc) {
        const int kb = (kc * 32 + (lane >> 4) * 8) * 2;
        const int ra0 = r0w + (lane & 15);
        const int ra1 = ra0 + 16;
        short8 a0 = *(short8*)((char*)sA + ((ra0 * 256 + kb) ^ ((ra0 & 7) << 4)));
        short8 a1 = *(short8*)((char*)sA + ((ra1 * 256 + kb) ^ ((ra1 & 7) << 4)));
#pragma unroll
        for (int nf = 0; nf < 8; ++nf) {
            const int rb = nf * 16 + (lane & 15);
            short8 b = *(short8*)((char*)sW + ((rb * 256 + kb) ^ ((rb & 7) << 4)));
            acc[0][nf] = __builtin_amdgcn_mfma_f32_16x16x32_bf16(a0, b, acc[0][nf], 0, 0, 0);
            acc[1][nf] = __builtin_amdgcn_mfma_f32_16x16x32_bf16(a1, b, acc[1][nf], 0, 0, 0);
        }
    }
    __syncthreads();

#pragma unroll
    for (int rf = 0; rf < 2; ++rf)
#pragma unroll
        for (int nf = 0; nf < 8; ++nf) {
            const int col = nf * 16 + (lane & 15);
            const float bias = b1[col];
#pragma unroll
            for (int i = 0; i < 4; ++i) {
                const int row = r0w + rf * 16 + (lane >> 4) * 4 + i;
                unsigned short hv = f2bf(tanhf(acc[rf][nf][i] + bias));
                *(unsigned short*)((char*)sA + ((row * 256 + col * 2) ^ ((row & 7) << 4))) = hv;
            }
        }
    for (int c = t; c < 2048; c += 256) {
        int r = c >> 4, k0 = (c & 15) * 8;
        ushort8_s v = *(const ushort8_s*)&Wt2[c * 8];
        *(ushort8_s*)((char*)sW + ((r * 256 + k0 * 2) ^ ((r & 7) << 4))) = v;
    }
    __syncthreads();

#pragma unroll
    for (int rf = 0; rf < 2; ++rf)
#pragma unroll
        for (int nf = 0; nf < 8; ++nf) acc[rf][nf] = (f32x4){0.f, 0.f, 0.f, 0.f};

#pragma unroll
    for (int kc = 0; kc < 4; ++kc) {
        const int kb = (kc * 32 + (lane >> 4) * 8) * 2;
        const int ra0 = r0w + (lane & 15);
        const int ra1 = ra0 + 16;
        short8 a0 = *(short8*)((char*)sA + ((ra0 * 256 + kb) ^ ((ra0 & 7) << 4)));
        short8 a1 = *(short8*)((char*)sA + ((ra1 * 256 + kb) ^ ((ra1 & 7) << 4)));
#pragma unroll
        for (int nf = 0; nf < 8; ++nf) {
            const int rb = nf * 16 + (lane & 15);
            short8 b = *(short8*)((char*)sW + ((rb * 256 + kb) ^ ((rb & 7) << 4)));
            acc[0][nf] = __builtin_amdgcn_mfma_f32_16x16x32_bf16(a0, b, acc[0][nf], 0, 0, 0);
            acc[1][nf] = __builtin_amdgcn_mfma_f32_16x16x32_bf16(a1, b, acc[1][nf], 0, 0, 0);
        }
    }

#pragma unroll
    for (int rf = 0; rf < 2; ++rf)
#pragma unroll
        for (int nf = 0; nf < 8; ++nf) {
            const int col = nf * 16 + (lane & 15);
            const float bias = b2[col];
#pragma unroll
            for (int i = 0; i < 4; ++i) {
                const int row = r0w + rf * 16 + (lane >> 4) * 4 + i;
                unsigned short hv = f2bf(acc[rf][nf][i] + bias);
                *(unsigned short*)((char*)sA + ((row * 256 + col * 2) ^ ((row & 7) << 4))) = hv;
            }
        }
    __syncthreads();

    for (int c = t; c < 2048; c += 256) {
        int r = c >> 4, k0 = (c & 15) * 8;
        int gr = row0 + r;
        if (gr < n) {
            ushort8_s v = *(ushort8_s*)((char*)sA + ((r * 256 + k0 * 2) ^ ((r & 7) << 4)));
            *(ushort8_s*)&hbf[(size_t)gr * D + k0] = v;
        }
    }
}

// ---- scan stage 1: local exclusive scan; degree; count->0 (cursor) ----
__global__ __launch_bounds__(256) void k_scan_local(int* __restrict__ count,
                                                    const int* __restrict__ selfc,
                                                    const int* __restrict__ indp,
                                                    float* __restrict__ degree,
                                                    int* __restrict__ row_ptr,
                                                    int* __restrict__ block_sums, int n) {
    __shared__ int s[256];
    const int t = threadIdx.x;
    const int base = blockIdx.x * SCAN_CHUNK + t * 4;
    const float mask = (indp[0] < 2) ? 1.0f : 0.0f;  // MASK = (1,1,0,0)
    int v[4];
#pragma unroll
    for (int j = 0; j < 4; ++j) {
        v[j] = 0;
        if (base + j < n) {
            int c = count[base + j];
            v[j] = c;
            degree[base + j] = (float)c + (mask - 1.0f) * (float)selfc[base + j];
            count[base + j] = 0;
        }
    }
    int sum4 = v[0] + v[1] + v[2] + v[3];
    s[t] = sum4;
    __syncthreads();
#pragma unroll
    for (int off = 1; off < 256; off <<= 1) {
        int x = (t >= off) ? s[t - off] : 0;
        __syncthreads();
        s[t] += x;
        __syncthreads();
    }
    int excl = s[t] - sum4;
    if (t == 255) block_sums[blockIdx.x] = s[255];
#pragma unroll
    for (int j = 0; j < 4; ++j) {
        if (base + j < n) row_ptr[base + j] = excl;
        excl += v[j];
    }
}

// ---- scan stage 2: exclusive-scan block sums (in place) ----
__global__ __launch_bounds__(128) void k_scan_blocks(int* __restrict__ block_sums, int nb) {
    __shared__ int s[128];
    const int t = threadIdx.x;
    int v = (t < nb) ? block_sums[t] : 0;
    s[t] = v;
    __syncthreads();
#pragma unroll
    for (int off = 1; off < 128; off <<= 1) {
        int x = (t >= off) ? s[t - off] : 0;
        __syncthreads();
        s[t] += x;
        __syncthreads();
    }
    if (t < nb) block_sums[t] = s[t] - v;
}

// ---- place: pairs[pos] = (dst, degree[dst]*W_edge[e]); row offset adds bsum inline ----
__global__ __launch_bounds__(256) void k_place(const int* __restrict__ src,
                                               const int* __restrict__ dst,
                                               const float* __restrict__ W_edge,
                                               const float* __restrict__ degree,
                                               const int* __restrict__ row_ptr,
                                               const int* __restrict__ bsum,
                                               int* __restrict__ cursor,
                                               float2* __restrict__ pairs, int E) {
    int e = blockIdx.x * 256 + threadIdx.x;
    if (e >= E) return;
    int s = src[e];
    int d = dst[e];
    int pos = row_ptr[s] + bsum[s >> 10] + atomicAdd(&cursor[s], 1);
    float2 p;
    p.x = __int_as_float(d);
    p.y = degree[d] * W_edge[e];
    pairs[pos] = p;
}

// ---- aggregate: 16 lanes/node; lane-parallel pair load + shfl broadcast ----
__global__ __launch_bounds__(256) void k_aggregate(const int* __restrict__ row_ptr,
                                                   const int* __restrict__ bsum,
                                                   const float2* __restrict__ pairs,
                                                   const unsigned short* __restrict__ hbf,
                                                   float* __restrict__ out, int n, int E) {
    long long tid = (long long)blockIdx.x * 256 + threadIdx.x;
    int node = (int)(tid >> 4);
    int li = (int)(tid & 15);
    int lane = threadIdx.x & 63;
    if (node >= n) return;
    int beg = row_ptr[node] + bsum[node >> 10];
    int end = (node + 1 == n) ? E : row_ptr[node + 1] + bsum[(node + 1) >> 10];

    float acc[8];
#pragma unroll
    for (int j = 0; j < 8; ++j) acc[j] = 0.f;
    float rsp = 0.f;
    const int gbase = lane & 48;  // first lane of this 16-lane group

    for (int base = beg; base < end; base += 16) {
        int m = end - base;
        m = (m > 16) ? 16 : m;
        float2 p = make_float2(0.f, 0.f);
        if (li < m) p = pairs[base + li];
        rsp += p.y;
        int i = 0;
        for (; i + 1 < m; i += 2) {
            int d0 = __float_as_int(__shfl(p.x, gbase + i));
            float w0 = __shfl(p.y, gbase + i);
            int d1 = __float_as_int(__shfl(p.x, gbase + i + 1));
            float w1 = __shfl(p.y, gbase + i + 1);
            uint4 h0 = *(const uint4*)&hbf[(size_t)d0 * D + li * 8];
            uint4 h1 = *(const uint4*)&hbf[(size_t)d1 * D + li * 8];
            acc[0] = fmaf(w0, bflo(h0.x), acc[0]); acc[1] = fmaf(w0, bfhi(h0.x), acc[1]);
            acc[2] = fmaf(w0, bflo(h0.y), acc[2]); acc[3] = fmaf(w0, bfhi(h0.y), acc[3]);
            acc[4] = fmaf(w0, bflo(h0.z), acc[4]); acc[5] = fmaf(w0, bfhi(h0.z), acc[5]);
            acc[6] = fmaf(w0, bflo(h0.w), acc[6]); acc[7] = fmaf(w0, bfhi(h0.w), acc[7]);
            acc[0] = fmaf(w1, bflo(h1.x), acc[0]); acc[1] = fmaf(w1, bfhi(h1.x), acc[1]);
            acc[2] = fmaf(w1, bflo(h1.y), acc[2]); acc[3] = fmaf(w1, bfhi(h1.y), acc[3]);
            acc[4] = fmaf(w1, bflo(h1.z), acc[4]); acc[5] = fmaf(w1, bfhi(h1.z), acc[5]);
            acc[6] = fmaf(w1, bflo(h1.w), acc[6]); acc[7] = fmaf(w1, bfhi(h1.w), acc[7]);
        }
        if (i < m) {
            int d0 = __float_as_int(__shfl(p.x, gbase + i));
            float w0 = __shfl(p.y, gbase + i);
            uint4 h0 = *(const uint4*)&hbf[(size_t)d0 * D + li * 8];
            acc[0] = fmaf(w0, bflo(h0.x), acc[0]); acc[1] = fmaf(w0, bfhi(h0.x), acc[1]);
            acc[2] = fmaf(w0, bflo(h0.y), acc[2]); acc[3] = fmaf(w0, bfhi(h0.y), acc[3]);
            acc[4] = fmaf(w0, bflo(h0.z), acc[4]); acc[5] = fmaf(w0, bfhi(h0.z), acc[5]);
            acc[6] = fmaf(w0, bflo(h0.w), acc[6]); acc[7] = fmaf(w0, bfhi(h0.w), acc[7]);
        }
    }
    // reduce rsp across the 16-lane group
    rsp += __shfl_xor(rsp, 1);
    rsp += __shfl_xor(rsp, 2);
    rsp += __shfl_xor(rsp, 4);
    rsp += __shfl_xor(rsp, 8);
    rsp = (rsp == 0.f) ? 1.f : rsp;
    float inv = 1.0f / rsp;
    float4 o0, o1;
    o0.x = acc[0] * inv; o0.y = acc[1] * inv; o0.z = acc[2] * inv; o0.w = acc[3] * inv;
    o1.x = acc[4] * inv; o1.y = acc[5] * inv; o1.z = acc[6] * inv; o1.w = acc[7] * inv;
    float* op = &out[(size_t)node * D + li * 8];
    *(float4*)op = o0;
    *(float4*)(op + 4) = o1;
}

extern "C" void kernel_launch(void* const* d_in, const int* in_sizes, int n_in,
                              void* d_out, int out_size, void* d_ws, size_t ws_size,
                              hipStream_t stream) {
    const float* feat   = (const float*)d_in[0];
    const float* W_edge = (const float*)d_in[1];
    const float* W1     = (const float*)d_in[2];
    const float* b1     = (const float*)d_in[3];
    const float* W2     = (const float*)d_in[4];
    const float* b2     = (const float*)d_in[5];
    const int* edge_src = (const int*)d_in[6];
    const int* edge_dst = (const int*)d_in[7];
    const int* indp     = (const int*)d_in[8];

    const int n = in_sizes[0] / D;   // 100000
    const int E = in_sizes[6];       // 600000
    const int nb = (n + SCAN_CHUNK - 1) / SCAN_CHUNK;  // 98

    // ws: count[n] | selfc[n] | row_ptr[n+1] | block_sums[128] | degree[n] |
    //     Wt1 u16[D*D] | Wt2 u16[D*D] | (align16) pairs f2[E] | hbf u16[n*D]
    char* ws = (char*)d_ws;
    int*   count      = (int*)ws;
    int*   selfc      = count + n;
    int*   row_ptr    = selfc + n;
    int*   block_sums = row_ptr + (n + 1);
    float* degree     = (float*)(block_sums + 128);
    unsigned short* Wt1 = (unsigned short*)(degree + n);
    unsigned short* Wt2 = Wt1 + D * D;
    size_t off = (size_t)((char*)(Wt2 + D * D) - ws);
    off = (off + 15) & ~(size_t)15;
    float2* pairs = (float2*)(ws + off);
    unsigned short* hbf = (unsigned short*)(pairs + E);

    const int zv4 = (2 * n) / 4;                 // int4 words to zero (count+selfc)
    const int zb = (zv4 + 255) / 256;            // 196
    k_prep<<<64 + zb, 256, 0, stream>>>(W1, W2, Wt1, Wt2, count, zv4);

    const int nm = (n + 127) / 128;              // 782 MLP blocks
    const int eb = (E + 255) / 256;              // 2344 count blocks
    k_mlp_count<<<nm + eb, 256, 0, stream>>>(feat, Wt1, Wt2, b1, b2, hbf, n,
                                             edge_src, edge_dst, count, selfc, E, nm);

    k_scan_local<<<nb, 256, 0, stream>>>(count, selfc, indp, degree, row_ptr, block_sums, n);
    k_scan_blocks<<<1, 128, 0, stream>>>(block_sums, nb);
    k_place<<<eb, 256, 0, stream>>>(edge_src, edge_dst, W_edge, degree, row_ptr, block_sums,
                                    count, pairs, E);

    long long athreads = (long long)n * 16;
    k_aggregate<<<(int)((athreads + 255) / 256), 256, 0, stream>>>(row_ptr, block_sums, pairs,
                                                                   hbf, (float*)d_out, n, E);
}

// Round 5
// 131.269 us; speedup vs baseline: 5.9120x; 1.0598x over previous
//
#include <hip/hip_runtime.h>

// MeanAggregator on MI355X.
// memset -> [Wprep|count] -> scan_local -> scan_blocks -> [mlp|place] -> aggregate.

constexpr int D = 128;
constexpr int SCAN_CHUNK = 1024;

typedef __attribute__((ext_vector_type(8))) short short8;
typedef __attribute__((ext_vector_type(4))) float f32x4;

__device__ __forceinline__ unsigned short f2bf(float x) {
    unsigned int u = __float_as_uint(x);
    u += 0x7fffu + ((u >> 16) & 1u);
    return (unsigned short)(u >> 16);
}
__device__ __forceinline__ float bflo(unsigned int u) { return __uint_as_float(u << 16); }
__device__ __forceinline__ float bfhi(unsigned int u) { return __uint_as_float(u & 0xffff0000u); }
__device__ __forceinline__ float fast_tanh(float x) {
    // tanh(x) = 1 - 2/(exp2(2*log2e*x)+1); exact limits at +/-inf
    float e = exp2f(x * 2.885390081777927f);
    return fmaf(-2.0f, __builtin_amdgcn_rcpf(e + 1.0f), 1.0f);
}

// ---- prep: W transpose->bf16 (blocks 0..63) | edge count (rest) ----
__global__ __launch_bounds__(256) void k_prep_count(const float* __restrict__ W1,
                                                    const float* __restrict__ W2,
                                                    unsigned short* __restrict__ Wt1,
                                                    unsigned short* __restrict__ Wt2,
                                                    const int* __restrict__ src,
                                                    const int* __restrict__ dst,
                                                    int* __restrict__ count,
                                                    int* __restrict__ selfc, int E) {
    int b = blockIdx.x;
    if (b < 64) {
        int t = b * 256 + threadIdx.x;  // t = k*D+n, coalesced read
        int k = t >> 7, nn = t & 127;
        Wt1[nn * D + k] = f2bf(W1[t]);
        Wt2[nn * D + k] = f2bf(W2[t]);
    } else {
        int e = (b - 64) * 256 + threadIdx.x;
        if (e < E) {
            int s = src[e];
            atomicAdd(&count[s], 1);
            if (s == dst[e]) atomicAdd(&selfc[s], 1);
        }
    }
}

// ---- scan stage 1: local exclusive scan; degree; count->0 (cursor) ----
__global__ __launch_bounds__(256) void k_scan_local(int* __restrict__ count,
                                                    const int* __restrict__ selfc,
                                                    const int* __restrict__ indp,
                                                    float* __restrict__ degree,
                                                    int* __restrict__ row_ptr,
                                                    int* __restrict__ block_sums, int n) {
    __shared__ int s[256];
    const int t = threadIdx.x;
    const int base = blockIdx.x * SCAN_CHUNK + t * 4;
    const float mask = (indp[0] < 2) ? 1.0f : 0.0f;  // MASK = (1,1,0,0)
    int v[4];
#pragma unroll
    for (int j = 0; j < 4; ++j) {
        v[j] = 0;
        if (base + j < n) {
            int c = count[base + j];
            v[j] = c;
            degree[base + j] = (float)c + (mask - 1.0f) * (float)selfc[base + j];
            count[base + j] = 0;
        }
    }
    int sum4 = v[0] + v[1] + v[2] + v[3];
    s[t] = sum4;
    __syncthreads();
#pragma unroll
    for (int off = 1; off < 256; off <<= 1) {
        int x = (t >= off) ? s[t - off] : 0;
        __syncthreads();
        s[t] += x;
        __syncthreads();
    }
    int excl = s[t] - sum4;
    if (t == 255) block_sums[blockIdx.x] = s[255];
#pragma unroll
    for (int j = 0; j < 4; ++j) {
        if (base + j < n) row_ptr[base + j] = excl;
        excl += v[j];
    }
}

// ---- scan stage 2: exclusive-scan block sums (in place) ----
__global__ __launch_bounds__(128) void k_scan_blocks(int* __restrict__ block_sums, int nb) {
    __shared__ int s[128];
    const int t = threadIdx.x;
    int v = (t < nb) ? block_sums[t] : 0;
    s[t] = v;
    __syncthreads();
#pragma unroll
    for (int off = 1; off < 128; off <<= 1) {
        int x = (t >= off) ? s[t - off] : 0;
        __syncthreads();
        s[t] += x;
        __syncthreads();
    }
    if (t < nb) block_sums[t] = s[t] - v;
}

// ---- fused: MLP (blocks < nm, wave-independent, no barriers) | place (rest) ----
__global__ __launch_bounds__(256) void k_mlp_place(
        const float* __restrict__ feat,
        const unsigned short* __restrict__ Wt1,
        const unsigned short* __restrict__ Wt2,
        const float* __restrict__ b1, const float* __restrict__ b2,
        unsigned short* __restrict__ hbf, int n, int nm,
        const int* __restrict__ src, const int* __restrict__ dst,
        const float* __restrict__ W_edge, const float* __restrict__ degree,
        const int* __restrict__ row_ptr, const int* __restrict__ bsum,
        int* __restrict__ cursor, float2* __restrict__ pairs, int E) {
    __shared__ unsigned short sT[128 * D];  // 32 KB; each wave uses its own 8 KB
    if (blockIdx.x >= nm) {
        int e = (blockIdx.x - nm) * 256 + threadIdx.x;
        if (e < E) {
            int s = src[e];
            int d = dst[e];
            int pos = row_ptr[s] + bsum[s >> 10] + atomicAdd(&cursor[s], 1);
            float2 p;
            p.x = __int_as_float(d);
            p.y = degree[d] * W_edge[e];
            pairs[pos] = p;
        }
        return;
    }
    const int t = threadIdx.x;
    const int lane = t & 63;
    const int w = t >> 6;
    const int rl0 = w * 32;                       // this wave's LDS row base
    const int row0 = blockIdx.x * 128 + rl0;      // this wave's global row base
    const int rA = lane & 15;
    const int ks = (lane >> 4) * 8;               // k sub-offset within a 32-wide slice

    f32x4 acc[2][8];
#pragma unroll
    for (int rf = 0; rf < 2; ++rf)
#pragma unroll
        for (int nf = 0; nf < 8; ++nf) acc[rf][nf] = (f32x4){0.f, 0.f, 0.f, 0.f};

    // GEMM1: A direct from feat (f32->bf16 in reg), B direct from Wt1 (L1-resident)
#pragma unroll
    for (int kc = 0; kc < 4; ++kc) {
        short8 a[2];
#pragma unroll
        for (int rf = 0; rf < 2; ++rf) {
            int gr = row0 + rf * 16 + rA;
            float4 f0 = make_float4(0.f, 0.f, 0.f, 0.f), f1 = f0;
            if (gr < n) {
                const float* fp = &feat[(size_t)gr * D + kc * 32 + ks];
                f0 = *(const float4*)fp;
                f1 = *(const float4*)(fp + 4);
            }
            short8 av;
            av[0] = (short)f2bf(f0.x); av[1] = (short)f2bf(f0.y);
            av[2] = (short)f2bf(f0.z); av[3] = (short)f2bf(f0.w);
            av[4] = (short)f2bf(f1.x); av[5] = (short)f2bf(f1.y);
            av[6] = (short)f2bf(f1.z); av[7] = (short)f2bf(f1.w);
            a[rf] = av;
        }
#pragma unroll
        for (int nf = 0; nf < 8; ++nf) {
            short8 b = *(const short8*)&Wt1[(nf * 16 + rA) * D + kc * 32 + ks];
            acc[0][nf] = __builtin_amdgcn_mfma_f32_16x16x32_bf16(a[0], b, acc[0][nf], 0, 0, 0);
            acc[1][nf] = __builtin_amdgcn_mfma_f32_16x16x32_bf16(a[1], b, acc[1][nf], 0, 0, 0);
        }
    }

    // tanh -> own 32 LDS rows (swizzled); wave-local, no barrier needed
#pragma unroll
    for (int rf = 0; rf < 2; ++rf)
#pragma unroll
        for (int nf = 0; nf < 8; ++nf) {
            const int col = nf * 16 + rA;
            const float bias = b1[col];
#pragma unroll
            for (int i = 0; i < 4; ++i) {
                const int rl = rl0 + rf * 16 + (lane >> 4) * 4 + i;
                unsigned short hv = f2bf(fast_tanh(acc[rf][nf][i] + bias));
                *(unsigned short*)((char*)sT + ((rl * 256 + col * 2) ^ ((rl & 7) << 4))) = hv;
            }
        }

#pragma unroll
    for (int rf = 0; rf < 2; ++rf)
#pragma unroll
        for (int nf = 0; nf < 8; ++nf) acc[rf][nf] = (f32x4){0.f, 0.f, 0.f, 0.f};

    // GEMM2: A from own LDS rows, B direct from Wt2 (L1-resident)
#pragma unroll
    for (int kc = 0; kc < 4; ++kc) {
        const int kb = (kc * 32 + ks) * 2;
        const int ra0 = rl0 + rA;
        const int ra1 = ra0 + 16;
        short8 a0 = *(short8*)((char*)sT + ((ra0 * 256 + kb) ^ ((ra0 & 7) << 4)));
        short8 a1 = *(short8*)((char*)sT + ((ra1 * 256 + kb) ^ ((ra1 & 7) << 4)));
#pragma unroll
        for (int nf = 0; nf < 8; ++nf) {
            short8 b = *(const short8*)&Wt2[(nf * 16 + rA) * D + kc * 32 + ks];
            acc[0][nf] = __builtin_amdgcn_mfma_f32_16x16x32_bf16(a0, b, acc[0][nf], 0, 0, 0);
            acc[1][nf] = __builtin_amdgcn_mfma_f32_16x16x32_bf16(a1, b, acc[1][nf], 0, 0, 0);
        }
    }

    // epilogue: +b2 -> bf16 -> own LDS rows (reads above already consumed)
#pragma unroll
    for (int rf = 0; rf < 2; ++rf)
#pragma unroll
        for (int nf = 0; nf < 8; ++nf) {
            const int col = nf * 16 + rA;
            const float bias = b2[col];
#pragma unroll
            for (int i = 0; i < 4; ++i) {
                const int rl = rl0 + rf * 16 + (lane >> 4) * 4 + i;
                unsigned short hv = f2bf(acc[rf][nf][i] + bias);
                *(unsigned short*)((char*)sT + ((rl * 256 + col * 2) ^ ((rl & 7) << 4))) = hv;
            }
        }

    // coalesced store of own 32 rows (wave-local ordering via lgkmcnt)
    for (int c = lane; c < 512; c += 64) {
        int r = c >> 4, k0 = (c & 15) * 8;
        int gr = row0 + r;
        if (gr < n) {
            int rl = rl0 + r;
            short8 v = *(short8*)((char*)sT + ((rl * 256 + k0 * 2) ^ ((rl & 7) << 4)));
            *(short8*)&hbf[(size_t)gr * D + k0] = v;
        }
    }
}

// ---- aggregate: 16 lanes/node; lane-parallel pair load + shfl broadcast ----
__global__ __launch_bounds__(256) void k_aggregate(const int* __restrict__ row_ptr,
                                                   const int* __restrict__ bsum,
                                                   const float2* __restrict__ pairs,
                                                   const unsigned short* __restrict__ hbf,
                                                   float* __restrict__ out, int n, int E) {
    long long tid = (long long)blockIdx.x * 256 + threadIdx.x;
    int node = (int)(tid >> 4);
    int li = (int)(tid & 15);
    int lane = threadIdx.x & 63;
    if (node >= n) return;
    int beg = row_ptr[node] + bsum[node >> 10];
    int end = (node + 1 == n) ? E : row_ptr[node + 1] + bsum[(node + 1) >> 10];

    float acc[8];
#pragma unroll
    for (int j = 0; j < 8; ++j) acc[j] = 0.f;
    float rsp = 0.f;
    const int gbase = lane & 48;

    for (int base = beg; base < end; base += 16) {
        int m = end - base;
        m = (m > 16) ? 16 : m;
        float2 p = make_float2(0.f, 0.f);
        if (li < m) p = pairs[base + li];
        rsp += p.y;
        int i = 0;
        for (; i + 1 < m; i += 2) {
            int d0 = __float_as_int(__shfl(p.x, gbase + i));
            float w0 = __shfl(p.y, gbase + i);
            int d1 = __float_as_int(__shfl(p.x, gbase + i + 1));
            float w1 = __shfl(p.y, gbase + i + 1);
            uint4 h0 = *(const uint4*)&hbf[(size_t)d0 * D + li * 8];
            uint4 h1 = *(const uint4*)&hbf[(size_t)d1 * D + li * 8];
            acc[0] = fmaf(w0, bflo(h0.x), acc[0]); acc[1] = fmaf(w0, bfhi(h0.x), acc[1]);
            acc[2] = fmaf(w0, bflo(h0.y), acc[2]); acc[3] = fmaf(w0, bfhi(h0.y), acc[3]);
            acc[4] = fmaf(w0, bflo(h0.z), acc[4]); acc[5] = fmaf(w0, bfhi(h0.z), acc[5]);
            acc[6] = fmaf(w0, bflo(h0.w), acc[6]); acc[7] = fmaf(w0, bfhi(h0.w), acc[7]);
            acc[0] = fmaf(w1, bflo(h1.x), acc[0]); acc[1] = fmaf(w1, bfhi(h1.x), acc[1]);
            acc[2] = fmaf(w1, bflo(h1.y), acc[2]); acc[3] = fmaf(w1, bfhi(h1.y), acc[3]);
            acc[4] = fmaf(w1, bflo(h1.z), acc[4]); acc[5] = fmaf(w1, bfhi(h1.z), acc[5]);
            acc[6] = fmaf(w1, bflo(h1.w), acc[6]); acc[7] = fmaf(w1, bfhi(h1.w), acc[7]);
        }
        if (i < m) {
            int d0 = __float_as_int(__shfl(p.x, gbase + i));
            float w0 = __shfl(p.y, gbase + i);
            uint4 h0 = *(const uint4*)&hbf[(size_t)d0 * D + li * 8];
            acc[0] = fmaf(w0, bflo(h0.x), acc[0]); acc[1] = fmaf(w0, bfhi(h0.x), acc[1]);
            acc[2] = fmaf(w0, bflo(h0.y), acc[2]); acc[3] = fmaf(w0, bfhi(h0.y), acc[3]);
            acc[4] = fmaf(w0, bflo(h0.z), acc[4]); acc[5] = fmaf(w0, bfhi(h0.z), acc[5]);
            acc[6] = fmaf(w0, bflo(h0.w), acc[6]); acc[7] = fmaf(w0, bfhi(h0.w), acc[7]);
        }
    }
    rsp += __shfl_xor(rsp, 1);
    rsp += __shfl_xor(rsp, 2);
    rsp += __shfl_xor(rsp, 4);
    rsp += __shfl_xor(rsp, 8);
    rsp = (rsp == 0.f) ? 1.f : rsp;
    float inv = 1.0f / rsp;
    float4 o0, o1;
    o0.x = acc[0] * inv; o0.y = acc[1] * inv; o0.z = acc[2] * inv; o0.w = acc[3] * inv;
    o1.x = acc[4] * inv; o1.y = acc[5] * inv; o1.z = acc[6] * inv; o1.w = acc[7] * inv;
    float* op = &out[(size_t)node * D + li * 8];
    *(float4*)op = o0;
    *(float4*)(op + 4) = o1;
}

extern "C" void kernel_launch(void* const* d_in, const int* in_sizes, int n_in,
                              void* d_out, int out_size, void* d_ws, size_t ws_size,
                              hipStream_t stream) {
    const float* feat   = (const float*)d_in[0];
    const float* W_edge = (const float*)d_in[1];
    const float* W1     = (const float*)d_in[2];
    const float* b1     = (const float*)d_in[3];
    const float* W2     = (const float*)d_in[4];
    const float* b2     = (const float*)d_in[5];
    const int* edge_src = (const int*)d_in[6];
    const int* edge_dst = (const int*)d_in[7];
    const int* indp     = (const int*)d_in[8];

    const int n = in_sizes[0] / D;   // 100000
    const int E = in_sizes[6];       // 600000
    const int nb = (n + SCAN_CHUNK - 1) / SCAN_CHUNK;  // 98

    // ws (16B-aligned front): Wt1 u16[D*D] | Wt2 u16[D*D] | degree f[n] | pairs f2[E] |
    //     hbf u16[n*D] | count i[n] | selfc i[n] | row_ptr i[n+1] | bsum i[128]
    char* ws = (char*)d_ws;
    unsigned short* Wt1 = (unsigned short*)ws;
    unsigned short* Wt2 = Wt1 + D * D;
    float* degree       = (float*)(Wt2 + D * D);
    float2* pairs       = (float2*)(degree + n);
    unsigned short* hbf = (unsigned short*)(pairs + E);
    int* count          = (int*)(hbf + (size_t)n * D);
    int* selfc          = count + n;
    int* row_ptr        = selfc + n;
    int* block_sums     = row_ptr + (n + 1);

    hipMemsetAsync(count, 0, (size_t)2 * n * sizeof(int), stream);

    const int eb = (E + 255) / 256;              // 2344
    k_prep_count<<<64 + eb, 256, 0, stream>>>(W1, W2, Wt1, Wt2,
                                              edge_src, edge_dst, count, selfc, E);

    k_scan_local<<<nb, 256, 0, stream>>>(count, selfc, indp, degree, row_ptr, block_sums, n);
    k_scan_blocks<<<1, 128, 0, stream>>>(block_sums, nb);

    const int nm = (n + 127) / 128;              // 782
    k_mlp_place<<<nm + eb, 256, 0, stream>>>(feat, Wt1, Wt2, b1, b2, hbf, n, nm,
                                             edge_src, edge_dst, W_edge, degree,
                                             row_ptr, block_sums, count, pairs, E);

    long long athreads = (long long)n * 16;
    k_aggregate<<<(int)((athreads + 255) / 256), 256, 0, stream>>>(row_ptr, block_sums, pairs,
                                                                   hbf, (float*)d_out, n, E);
}